// Round 1
// baseline (1583.029 us; speedup 1.0000x reference)
//
#include <hip/hip_runtime.h>
#include <math.h>

#define BB_   16
#define NN_   2048
#define CDIM  10
#define KNN   16
#define NNODES (BB_*NN_)      // 32768
#define NEDGES (NNODES*KNN)   // 524288

// ---------------- prep: squared norms + zero indeg ----------------
__global__ __launch_bounds__(256) void prep_kernel(const float* __restrict__ x,
                                                   float* __restrict__ x2,
                                                   int* __restrict__ indeg) {
    int g = blockIdx.x * 256 + threadIdx.x;
    if (g >= NNODES) return;
    const float* xr = x + (size_t)g * CDIM;
    float s = 0.f;
#pragma unroll
    for (int c = 0; c < CDIM; ++c) s = fmaf(xr[c], xr[c], s);
    x2[g] = s;
    indeg[g] = 0;
}

// ---------------- kNN: one wave per row ----------------
__global__ __launch_bounds__(256) void knn_kernel(const float* __restrict__ x,
                                                  const float* __restrict__ x2,
                                                  int* __restrict__ nbors,
                                                  int* __restrict__ indeg) {
    __shared__ float sd[KNN][4][64];
    __shared__ int   si[KNN][4][64];
    const int wv   = threadIdx.x >> 6;
    const int lane = threadIdx.x & 63;
    const int g  = blockIdx.x * 4 + wv;   // global row (node)
    const int bb = g >> 11;               // batch
    const int il = g & (NN_ - 1);         // local row
    const float* xg = x + (size_t)g * CDIM;
    float xr[CDIM];
#pragma unroll
    for (int c = 0; c < CDIM; ++c) xr[c] = xg[c];
    const float  x2g = x2[g];
    const float* xb  = x + (size_t)bb * NN_ * CDIM;
    const float* x2b = x2 + bb * NN_;

    float ld[KNN]; int li[KNN];
#pragma unroll
    for (int p = 0; p < KNN; ++p) { ld[p] = INFINITY; li[p] = 0x7fffffff; }

    for (int jj = lane; jj < NN_; jj += 64) {
        if (jj == il) continue;
        const float* xc = xb + (size_t)jj * CDIM;
        float dot = 0.f;
#pragma unroll
        for (int c = 0; c < CDIM; ++c) dot = fmaf(xr[c], xc[c], dot);
        float d = x2g + x2b[jj] - 2.f * dot;
        if (d < ld[KNN - 1]) {
            ld[KNN - 1] = d; li[KNN - 1] = jj;
#pragma unroll
            for (int p = KNN - 1; p > 0; --p) {
                bool sw = (ld[p] < ld[p - 1]) || (ld[p] == ld[p - 1] && li[p] < li[p - 1]);
                if (sw) {
                    float td = ld[p]; ld[p] = ld[p - 1]; ld[p - 1] = td;
                    int   ti = li[p]; li[p] = li[p - 1]; li[p - 1] = ti;
                }
            }
        }
    }

    // dump sorted per-lane lists to LDS (layout: [pos][wave][lane] -> conflict-free)
#pragma unroll
    for (int p = 0; p < KNN; ++p) { sd[p][wv][lane] = ld[p]; si[p][wv][lane] = li[p]; }

    // 16-round head-pointer merge via wave argmin
    int head = 0;
    for (int r = 0; r < KNN; ++r) {
        float v  = (head < KNN) ? sd[head][wv][lane] : INFINITY;
        int   vi = (head < KNN) ? si[head][wv][lane] : 0x7fffffff;
        int   vl = lane;
#pragma unroll
        for (int m = 32; m >= 1; m >>= 1) {
            float ov = __shfl_xor(v, m, 64);
            int   oi = __shfl_xor(vi, m, 64);
            int   ol = __shfl_xor(vl, m, 64);
            if (ov < v || (ov == v && oi < vi)) { v = ov; vi = oi; vl = ol; }
        }
        if (lane == vl) head++;
        if (lane == 31) nbors[(size_t)g * KNN + r] = bb * NN_ + vi;
        if (lane == 0)  atomicAdd(&indeg[bb * NN_ + vi], 1);
    }
}

// ---------------- exclusive scan over indeg (single block) ----------------
__global__ __launch_bounds__(1024) void scan_kernel(const int* __restrict__ indeg,
                                                    int* __restrict__ offs,
                                                    int* __restrict__ cursor) {
    __shared__ int part[1024];
    int t = threadIdx.x;
    int base = t * 32;
    int loc[32];
    int s = 0;
#pragma unroll
    for (int i = 0; i < 32; ++i) { loc[i] = indeg[base + i]; s += loc[i]; }
    part[t] = s;
    __syncthreads();
    for (int d = 1; d < 1024; d <<= 1) {
        int add = (t >= d) ? part[t - d] : 0;
        __syncthreads();
        part[t] += add;
        __syncthreads();
    }
    int run = part[t] - s;  // exclusive base for this thread's chunk
#pragma unroll
    for (int i = 0; i < 32; ++i) {
        offs[base + i] = run; cursor[base + i] = run; run += loc[i];
    }
    if (t == 1023) offs[NNODES] = run;
}

// ---------------- fill reverse adjacency ----------------
__global__ __launch_bounds__(256) void fill_kernel(const int* __restrict__ nbors,
                                                   int* __restrict__ cursor,
                                                   int* __restrict__ rev) {
    int e = blockIdx.x * 256 + threadIdx.x;
    if (e >= NEDGES) return;
    int dst = nbors[e];
    int src = e >> 4;                 // KNN == 16
    int pos = atomicAdd(&cursor[dst], 1);
    rev[pos] = src;
}

// ---------------- fused aggregate + dual linear (+ReLU) ----------------
// out[j] = agg[j] @ wrel + in[j] @ wroot + bias ; agg[j] = sum_{s in rev[j]} in[s]
template<int CIN, int COUT, int GS, bool RELU>
__global__ __launch_bounds__(256) void layer_kernel(const float* __restrict__ in,
                                                    const float* __restrict__ wrel,
                                                    const float* __restrict__ wroot,
                                                    const float* __restrict__ bias,
                                                    const int* __restrict__ offs,
                                                    const int* __restrict__ rev,
                                                    float* __restrict__ out) {
    constexpr int NT = 8;                 // nodes per block
    __shared__ float s_ai[NT][CIN][2];    // [0]=agg, [1]=own row
    const int j0 = blockIdx.x * NT;
    const int t  = threadIdx.x;

    // ---- staging: groups of GS threads each own nodes round-robin ----
    constexpr int NG = 256 / GS;
    const int grp = t / GS, cc = t % GS;
    for (int nt = grp; nt < NT; nt += NG) {
        const int j = j0 + nt;
        if (cc < CIN) s_ai[nt][cc][1] = in[(size_t)j * CIN + cc];
        float agg = 0.f;
        const int e0 = offs[j], e1 = offs[j + 1];
        for (int e = e0; e < e1; ++e) {
            const int s = rev[e];
            if (cc < CIN) agg += in[(size_t)s * CIN + cc];
        }
        if (cc < CIN) s_ai[nt][cc][0] = agg;
    }
    __syncthreads();

    // ---- compute: thread = (channel c, replica r); each thread does NPT nodes ----
    constexpr int REP = 256 / COUT;
    constexpr int NPT = NT / REP;
    const int c = t % COUT, r = t / COUT;
    float acc[NPT];
#pragma unroll
    for (int u = 0; u < NPT; ++u) acc[u] = bias[c];
#pragma unroll 4
    for (int k = 0; k < CIN; ++k) {
        const float wrv = wrel[k * COUT + c];
        const float wov = wroot[k * COUT + c];
#pragma unroll
        for (int u = 0; u < NPT; ++u) {
            const int nt = r + u * REP;
            acc[u] = fmaf(s_ai[nt][k][0], wrv, acc[u]);
            acc[u] = fmaf(s_ai[nt][k][1], wov, acc[u]);
        }
    }
#pragma unroll
    for (int u = 0; u < NPT; ++u) {
        const int nt = r + u * REP;
        float v = acc[u];
        if (RELU) v = fmaxf(v, 0.f);
        out[(size_t)(j0 + nt) * COUT + c] = v;
    }
}

// ---------------- final bilinear: out[b,i,j] = dot64(h[b,i], h[b,j]) ----------------
__global__ __launch_bounds__(256) void edge_kernel(const float* __restrict__ h,
                                                   float* __restrict__ out) {
    __shared__ float tI[64][65];
    __shared__ float tJ[64][65];
    const int b  = blockIdx.z;
    const int i0 = blockIdx.y * 64;
    const int j0 = blockIdx.x * 64;
    const float* hb = h + (size_t)b * NN_ * 64;
    const int t  = threadIdx.x;
    const int lr = t >> 2, lc = (t & 3) * 16;
#pragma unroll
    for (int u = 0; u < 16; u += 4) {
        float4 vI = *(const float4*)(hb + (size_t)(i0 + lr) * 64 + lc + u);
        float4 vJ = *(const float4*)(hb + (size_t)(j0 + lr) * 64 + lc + u);
        tI[lr][lc + u + 0] = vI.x; tI[lr][lc + u + 1] = vI.y;
        tI[lr][lc + u + 2] = vI.z; tI[lr][lc + u + 3] = vI.w;
        tJ[lr][lc + u + 0] = vJ.x; tJ[lr][lc + u + 1] = vJ.y;
        tJ[lr][lc + u + 2] = vJ.z; tJ[lr][lc + u + 3] = vJ.w;
    }
    __syncthreads();

    const int ti = (t >> 4) * 4;
    const int tj = (t & 15) * 4;
    float acc[4][4];
#pragma unroll
    for (int u = 0; u < 4; ++u)
#pragma unroll
        for (int v = 0; v < 4; ++v) acc[u][v] = 0.f;

#pragma unroll 4
    for (int k = 0; k < 64; ++k) {
        float a0 = tI[ti + 0][k], a1 = tI[ti + 1][k], a2 = tI[ti + 2][k], a3 = tI[ti + 3][k];
        float b0 = tJ[tj + 0][k], b1 = tJ[tj + 1][k], b2 = tJ[tj + 2][k], b3 = tJ[tj + 3][k];
        acc[0][0] = fmaf(a0, b0, acc[0][0]); acc[0][1] = fmaf(a0, b1, acc[0][1]);
        acc[0][2] = fmaf(a0, b2, acc[0][2]); acc[0][3] = fmaf(a0, b3, acc[0][3]);
        acc[1][0] = fmaf(a1, b0, acc[1][0]); acc[1][1] = fmaf(a1, b1, acc[1][1]);
        acc[1][2] = fmaf(a1, b2, acc[1][2]); acc[1][3] = fmaf(a1, b3, acc[1][3]);
        acc[2][0] = fmaf(a2, b0, acc[2][0]); acc[2][1] = fmaf(a2, b1, acc[2][1]);
        acc[2][2] = fmaf(a2, b2, acc[2][2]); acc[2][3] = fmaf(a2, b3, acc[2][3]);
        acc[3][0] = fmaf(a3, b0, acc[3][0]); acc[3][1] = fmaf(a3, b1, acc[3][1]);
        acc[3][2] = fmaf(a3, b2, acc[3][2]); acc[3][3] = fmaf(a3, b3, acc[3][3]);
    }

#pragma unroll
    for (int u = 0; u < 4; ++u) {
        float4 v4; v4.x = acc[u][0]; v4.y = acc[u][1]; v4.z = acc[u][2]; v4.w = acc[u][3];
        *(float4*)(out + ((size_t)b * NN_ + (i0 + ti + u)) * NN_ + (j0 + tj)) = v4;
    }
}

extern "C" void kernel_launch(void* const* d_in, const int* in_sizes, int n_in,
                              void* d_out, int out_size, void* d_ws, size_t ws_size,
                              hipStream_t stream) {
    (void)in_sizes; (void)n_in; (void)out_size; (void)ws_size;
    const float* x = (const float*)d_in[0];
    const float* wr[4] = {(const float*)d_in[1],  (const float*)d_in[4],
                          (const float*)d_in[7],  (const float*)d_in[10]};
    const float* wo[4] = {(const float*)d_in[2],  (const float*)d_in[5],
                          (const float*)d_in[8],  (const float*)d_in[11]};
    const float* bs[4] = {(const float*)d_in[3],  (const float*)d_in[6],
                          (const float*)d_in[9],  (const float*)d_in[12]};
    float* out = (float*)d_out;

    char* w = (char*)d_ws;
    size_t o = 0;
    auto alloc = [&](size_t bytes) { void* p = w + o; o = (o + bytes + 255) & ~(size_t)255; return p; };
    int*   nbors  = (int*)  alloc((size_t)NEDGES * 4);
    int*   indeg  = (int*)  alloc((size_t)NNODES * 4);
    int*   offs   = (int*)  alloc((size_t)(NNODES + 1) * 4);
    int*   cursor = (int*)  alloc((size_t)NNODES * 4);
    int*   rev    = (int*)  alloc((size_t)NEDGES * 4);
    float* x2     = (float*)alloc((size_t)NNODES * 4);
    float* hA     = (float*)alloc((size_t)NNODES * 128 * 4);
    float* hB     = (float*)alloc((size_t)NNODES * 128 * 4);

    prep_kernel<<<NNODES / 256, 256, 0, stream>>>(x, x2, indeg);
    knn_kernel<<<NNODES / 4, 256, 0, stream>>>(x, x2, nbors, indeg);
    scan_kernel<<<1, 1024, 0, stream>>>(indeg, offs, cursor);
    fill_kernel<<<NEDGES / 256, 256, 0, stream>>>(nbors, cursor, rev);

    layer_kernel<CDIM, 128, 16,  true ><<<NNODES / 8, 256, 0, stream>>>(x,  wr[0], wo[0], bs[0], offs, rev, hA);
    layer_kernel<128,  128, 128, true ><<<NNODES / 8, 256, 0, stream>>>(hA, wr[1], wo[1], bs[1], offs, rev, hB);
    layer_kernel<128,  128, 128, true ><<<NNODES / 8, 256, 0, stream>>>(hB, wr[2], wo[2], bs[2], offs, rev, hA);
    layer_kernel<128,  64,  128, false><<<NNODES / 8, 256, 0, stream>>>(hA, wr[3], wo[3], bs[3], offs, rev, hB);

    edge_kernel<<<dim3(32, 32, 16), 256, 0, stream>>>(hB, out);
}

// Round 2
// 1086.228 us; speedup vs baseline: 1.4574x; 1.4574x over previous
//
#include <hip/hip_runtime.h>
#include <math.h>

#define BB_   16
#define NN_   2048
#define CDIM  10
#define KNN   16
#define NNODES (BB_*NN_)      // 32768
#define NEDGES (NNODES*KNN)   // 524288

// ---------------- prep: squared norms + zero indeg ----------------
__global__ __launch_bounds__(256) void prep_kernel(const float* __restrict__ x,
                                                   float* __restrict__ x2,
                                                   int* __restrict__ indeg) {
    int g = blockIdx.x * 256 + threadIdx.x;
    if (g >= NNODES) return;
    const float* xr = x + (size_t)g * CDIM;
    float s = 0.f;
#pragma unroll
    for (int c = 0; c < CDIM; ++c) s = fmaf(xr[c], xr[c], s);
    x2[g] = s;
    indeg[g] = 0;
}

// order-preserving float->uint transform (handles negatives exactly)
__device__ __forceinline__ unsigned fkey(float f) {
    unsigned u = __float_as_uint(f);
    return ((int)u >= 0) ? (u ^ 0x80000000u) : ~u;
}

// full bitonic sort of (hi,lo) u64 keys across 64 lanes, ascending.
// keys MUST be unique (ties break permutation property).
__device__ __forceinline__ void bitonic64(unsigned& hi, unsigned& lo, int lane) {
#pragma unroll
    for (int k = 2; k <= 64; k <<= 1) {
#pragma unroll
        for (int j = k >> 1; j > 0; j >>= 1) {
            unsigned ohi = __shfl_xor(hi, j, 64);
            unsigned olo = __shfl_xor(lo, j, 64);
            bool up    = ((lane & k) == 0);
            bool lower = ((lane & j) == 0);
            bool oless = (ohi < hi) || (ohi == hi && olo < lo);  // other < mine
            bool take  = (lower == up) ? oless : !oless;
            hi = take ? ohi : hi;
            lo = take ? olo : lo;
        }
    }
}

// ---------------- kNN: one wave per row, threshold-select ----------------
// Per lane: 32 candidates (stride-64). Track lane min during distance pass.
// M16 = 16th smallest of 64 lane-minima bounds the true 16th distance from
// above (16 distinct candidates <= M16). Compact all candidates <= M16
// (C>=16, E[C]~20) to LDS, bitonic-sort, take 16. Fallback (C>64): exact
// round-based extraction from registers (never taken for random data).
__global__ __launch_bounds__(256) void knn_kernel(const float* __restrict__ x,
                                                  const float* __restrict__ x2,
                                                  int* __restrict__ nbors,
                                                  int* __restrict__ indeg) {
    __shared__ unsigned s_hi[4][64];
    __shared__ unsigned s_lo[4][64];
    const int wv   = threadIdx.x >> 6;
    const int lane = threadIdx.x & 63;
    const int g  = blockIdx.x * 4 + wv;   // global row (node)
    const int bb = g >> 11;               // batch
    const int il = g & (NN_ - 1);         // local row index

    // own row (float2 x5 = 10 floats, 8B aligned since rows are 40B)
    const float2* xg2 = (const float2*)(x) + (size_t)g * 5;
    float2 xp0 = xg2[0], xp1 = xg2[1], xp2 = xg2[2], xp3 = xg2[3], xp4 = xg2[4];
    const float  x2g = x2[g];
    const float2* xb2 = (const float2*)(x + (size_t)bb * NN_ * CDIM);
    const float*  x2b = x2 + bb * NN_;

    unsigned ud[32];
    unsigned min_hi = 0xFFFFFFFFu, min_lo = 0xFFFFFFFFu;
#pragma unroll
    for (int s = 0; s < 32; ++s) {
        const int jj = s * 64 + lane;
        const float2* xc = xb2 + (size_t)jj * 5;
        float2 c0 = xc[0], c1 = xc[1], c2 = xc[2], c3 = xc[3], c4 = xc[4];
        float dot = xp0.x * c0.x + xp0.y * c0.y;
        dot = fmaf(xp1.x, c1.x, dot); dot = fmaf(xp1.y, c1.y, dot);
        dot = fmaf(xp2.x, c2.x, dot); dot = fmaf(xp2.y, c2.y, dot);
        dot = fmaf(xp3.x, c3.x, dot); dot = fmaf(xp3.y, c3.y, dot);
        dot = fmaf(xp4.x, c4.x, dot); dot = fmaf(xp4.y, c4.y, dot);
        float d = x2g + x2b[jj] - 2.f * dot;
        unsigned u = fkey(d);
        if (jj == il) u = 0xFFFFFFFFu;    // exclude self (strict max key)
        ud[s] = u;
        bool less = (u < min_hi) || (u == min_hi && (unsigned)jj < min_lo);
        min_hi = less ? u : min_hi;
        min_lo = less ? (unsigned)jj : min_lo;
    }

    // threshold M16 = 16th smallest lane-min
    unsigned bh = min_hi, bl = min_lo;
    bitonic64(bh, bl, lane);
    const unsigned m_hi = __shfl(bh, 15, 64);
    const unsigned m_lo = __shfl(bl, 15, 64);

    // count qualifying candidates per lane
    int c = 0;
#pragma unroll
    for (int s = 0; s < 32; ++s) {
        const unsigned jj = (unsigned)(s * 64 + lane);
        const unsigned u  = ud[s];
        bool q = (u < m_hi) || (u == m_hi && jj <= m_lo);
        c += q ? 1 : 0;
    }
    // exclusive prefix across lanes
    int pos = c;
#pragma unroll
    for (int m = 1; m < 64; m <<= 1) {
        int o = __shfl_up(pos, m, 64);
        if (lane >= m) pos += o;
    }
    const int total = __shfl(pos, 63, 64);
    pos -= c;

    if (total <= 64) {
        // compact to LDS (wave-private region; same-wave ds ordering via lgkmcnt)
#pragma unroll
        for (int s = 0; s < 32; ++s) {
            const unsigned jj = (unsigned)(s * 64 + lane);
            const unsigned u  = ud[s];
            bool q = (u < m_hi) || (u == m_hi && jj <= m_lo);
            if (q) { s_hi[wv][pos] = u; s_lo[wv][pos] = jj; pos++; }
        }
        unsigned u2 = (lane < total) ? s_hi[wv][lane] : 0xFFFFFFFFu;
        unsigned l2 = (lane < total) ? s_lo[wv][lane] : (0x80000000u + (unsigned)lane);
        bitonic64(u2, l2, lane);
        if (lane < KNN) {
            const int jglob = bb * NN_ + (int)l2;
            nbors[(size_t)g * KNN + lane] = jglob;
            atomicAdd(&indeg[jglob], 1);
        }
    } else {
        // exact fallback: 16 rounds of masked rescan + wave argmin (rare)
        unsigned taken = 0;
        for (int r = 0; r < KNN; ++r) {
            unsigned b_hi = 0xFFFFFFFFu, b_lo = 0xFFFFFFFFu;
#pragma unroll
            for (int s = 0; s < 32; ++s) {
                const unsigned jj = (unsigned)(s * 64 + lane);
                const unsigned u  = ud[s];
                bool avail = ((taken >> s) & 1u) == 0u;
                bool less  = avail && ((u < b_hi) || (u == b_hi && jj < b_lo));
                b_hi = less ? u : b_hi;
                b_lo = less ? jj : b_lo;
            }
            unsigned w_hi = b_hi, w_lo = b_lo;
#pragma unroll
            for (int m = 32; m >= 1; m >>= 1) {
                unsigned oh = __shfl_xor(w_hi, m, 64);
                unsigned ol = __shfl_xor(w_lo, m, 64);
                bool less = (oh < w_hi) || (oh == w_hi && ol < w_lo);
                w_hi = less ? oh : w_hi;
                w_lo = less ? ol : w_lo;
            }
            if (b_hi == w_hi && b_lo == w_lo) {   // unique winner lane
                taken |= 1u << (b_lo >> 6);
                const int jglob = bb * NN_ + (int)w_lo;
                nbors[(size_t)g * KNN + r] = jglob;
                atomicAdd(&indeg[jglob], 1);
            }
        }
    }
}

// ---------------- exclusive scan over indeg (single block) ----------------
__global__ __launch_bounds__(1024) void scan_kernel(const int* __restrict__ indeg,
                                                    int* __restrict__ offs,
                                                    int* __restrict__ cursor) {
    __shared__ int part[1024];
    int t = threadIdx.x;
    int base = t * 32;
    int loc[32];
    int s = 0;
#pragma unroll
    for (int i = 0; i < 32; ++i) { loc[i] = indeg[base + i]; s += loc[i]; }
    part[t] = s;
    __syncthreads();
    for (int d = 1; d < 1024; d <<= 1) {
        int add = (t >= d) ? part[t - d] : 0;
        __syncthreads();
        part[t] += add;
        __syncthreads();
    }
    int run = part[t] - s;
#pragma unroll
    for (int i = 0; i < 32; ++i) {
        offs[base + i] = run; cursor[base + i] = run; run += loc[i];
    }
    if (t == 1023) offs[NNODES] = run;
}

// ---------------- fill reverse adjacency ----------------
__global__ __launch_bounds__(256) void fill_kernel(const int* __restrict__ nbors,
                                                   int* __restrict__ cursor,
                                                   int* __restrict__ rev) {
    int e = blockIdx.x * 256 + threadIdx.x;
    if (e >= NEDGES) return;
    int dst = nbors[e];
    int src = e >> 4;                 // KNN == 16
    int pos = atomicAdd(&cursor[dst], 1);
    rev[pos] = src;
}

// ---------------- fused aggregate + dual linear (+ReLU) ----------------
template<int CIN, int COUT, int GS, bool RELU>
__global__ __launch_bounds__(256) void layer_kernel(const float* __restrict__ in,
                                                    const float* __restrict__ wrel,
                                                    const float* __restrict__ wroot,
                                                    const float* __restrict__ bias,
                                                    const int* __restrict__ offs,
                                                    const int* __restrict__ rev,
                                                    float* __restrict__ out) {
    constexpr int NT = 8;                 // nodes per block
    __shared__ float s_ai[NT][CIN][2];    // [0]=agg, [1]=own row
    const int j0 = blockIdx.x * NT;
    const int t  = threadIdx.x;

    constexpr int NG = 256 / GS;
    const int grp = t / GS, cc = t % GS;
    for (int nt = grp; nt < NT; nt += NG) {
        const int j = j0 + nt;
        if (cc < CIN) s_ai[nt][cc][1] = in[(size_t)j * CIN + cc];
        float agg = 0.f;
        const int e0 = offs[j], e1 = offs[j + 1];
        for (int e = e0; e < e1; ++e) {
            const int s = rev[e];
            if (cc < CIN) agg += in[(size_t)s * CIN + cc];
        }
        if (cc < CIN) s_ai[nt][cc][0] = agg;
    }
    __syncthreads();

    constexpr int REP = 256 / COUT;
    constexpr int NPT = NT / REP;
    const int c = t % COUT, r = t / COUT;
    float acc[NPT];
#pragma unroll
    for (int u = 0; u < NPT; ++u) acc[u] = bias[c];
#pragma unroll 4
    for (int k = 0; k < CIN; ++k) {
        const float wrv = wrel[k * COUT + c];
        const float wov = wroot[k * COUT + c];
#pragma unroll
        for (int u = 0; u < NPT; ++u) {
            const int nt = r + u * REP;
            acc[u] = fmaf(s_ai[nt][k][0], wrv, acc[u]);
            acc[u] = fmaf(s_ai[nt][k][1], wov, acc[u]);
        }
    }
#pragma unroll
    for (int u = 0; u < NPT; ++u) {
        const int nt = r + u * REP;
        float v = acc[u];
        if (RELU) v = fmaxf(v, 0.f);
        out[(size_t)(j0 + nt) * COUT + c] = v;
    }
}

// ---------------- final bilinear: out[b,i,j] = dot64(h[b,i], h[b,j]) ----------------
// k-major (transposed) LDS tiles so fragment loads are ds_read_b128.
// Tile: 64 (i) x 128 (j); thread computes 4x8.
__global__ __launch_bounds__(256) void edge_kernel(const float* __restrict__ h,
                                                   float* __restrict__ out) {
    __shared__ float tI[64][68];    // [k][i], pad 68 keeps b128 align, reads conflict-free
    __shared__ float tJ[64][132];   // [k][j]
    const int b  = blockIdx.z;
    const int i0 = blockIdx.y * 64;
    const int j0 = blockIdx.x * 128;
    const float* hb = h + (size_t)b * NN_ * 64;
    const int t = threadIdx.x;

    // stage I tile: 64 rows x 64 k -> tI[k][i]
    {
        const int ir = t >> 2, seg = t & 3;     // 4 float4s per thread
        const float* src = hb + (size_t)(i0 + ir) * 64 + seg * 16;
#pragma unroll
        for (int v = 0; v < 4; ++v) {
            float4 f = *(const float4*)(src + v * 4);
            const int c = seg * 16 + v * 4;
            tI[c + 0][ir] = f.x; tI[c + 1][ir] = f.y;
            tI[c + 2][ir] = f.z; tI[c + 3][ir] = f.w;
        }
    }
    // stage J tile: 128 rows x 64 k -> tJ[k][j]
    {
        const int jr = t >> 1, seg = t & 1;     // 8 float4s per thread
        const float* src = hb + (size_t)(j0 + jr) * 64 + seg * 32;
#pragma unroll
        for (int v = 0; v < 8; ++v) {
            float4 f = *(const float4*)(src + v * 4);
            const int c = seg * 32 + v * 4;
            tJ[c + 0][jr] = f.x; tJ[c + 1][jr] = f.y;
            tJ[c + 2][jr] = f.z; tJ[c + 3][jr] = f.w;
        }
    }
    __syncthreads();

    const int ti = (t >> 4) * 4;      // 0..60
    const int tj = (t & 15) * 8;      // 0..120
    float acc[4][8];
#pragma unroll
    for (int u = 0; u < 4; ++u)
#pragma unroll
        for (int v = 0; v < 8; ++v) acc[u][v] = 0.f;

#pragma unroll 8
    for (int k = 0; k < 64; ++k) {
        float4 a  = *(const float4*)(&tI[k][ti]);
        float4 b0 = *(const float4*)(&tJ[k][tj]);
        float4 b1 = *(const float4*)(&tJ[k][tj + 4]);
        float av[4] = {a.x, a.y, a.z, a.w};
        float bv[8] = {b0.x, b0.y, b0.z, b0.w, b1.x, b1.y, b1.z, b1.w};
#pragma unroll
        for (int u = 0; u < 4; ++u)
#pragma unroll
            for (int v = 0; v < 8; ++v) acc[u][v] = fmaf(av[u], bv[v], acc[u][v]);
    }

#pragma unroll
    for (int u = 0; u < 4; ++u) {
        float* dst = out + ((size_t)b * NN_ + (i0 + ti + u)) * NN_ + (j0 + tj);
        float4 w0; w0.x = acc[u][0]; w0.y = acc[u][1]; w0.z = acc[u][2]; w0.w = acc[u][3];
        float4 w1; w1.x = acc[u][4]; w1.y = acc[u][5]; w1.z = acc[u][6]; w1.w = acc[u][7];
        *(float4*)(dst)     = w0;
        *(float4*)(dst + 4) = w1;
    }
}

extern "C" void kernel_launch(void* const* d_in, const int* in_sizes, int n_in,
                              void* d_out, int out_size, void* d_ws, size_t ws_size,
                              hipStream_t stream) {
    (void)in_sizes; (void)n_in; (void)out_size; (void)ws_size;
    const float* x = (const float*)d_in[0];
    const float* wr[4] = {(const float*)d_in[1],  (const float*)d_in[4],
                          (const float*)d_in[7],  (const float*)d_in[10]};
    const float* wo[4] = {(const float*)d_in[2],  (const float*)d_in[5],
                          (const float*)d_in[8],  (const float*)d_in[11]};
    const float* bs[4] = {(const float*)d_in[3],  (const float*)d_in[6],
                          (const float*)d_in[9],  (const float*)d_in[12]};
    float* out = (float*)d_out;

    char* w = (char*)d_ws;
    size_t o = 0;
    auto alloc = [&](size_t bytes) { void* p = w + o; o = (o + bytes + 255) & ~(size_t)255; return p; };
    int*   nbors  = (int*)  alloc((size_t)NEDGES * 4);
    int*   indeg  = (int*)  alloc((size_t)NNODES * 4);
    int*   offs   = (int*)  alloc((size_t)(NNODES + 1) * 4);
    int*   cursor = (int*)  alloc((size_t)NNODES * 4);
    int*   rev    = (int*)  alloc((size_t)NEDGES * 4);
    float* x2     = (float*)alloc((size_t)NNODES * 4);
    float* hA     = (float*)alloc((size_t)NNODES * 128 * 4);
    float* hB     = (float*)alloc((size_t)NNODES * 128 * 4);

    prep_kernel<<<NNODES / 256, 256, 0, stream>>>(x, x2, indeg);
    knn_kernel<<<NNODES / 4, 256, 0, stream>>>(x, x2, nbors, indeg);
    scan_kernel<<<1, 1024, 0, stream>>>(indeg, offs, cursor);
    fill_kernel<<<NEDGES / 256, 256, 0, stream>>>(nbors, cursor, rev);

    layer_kernel<CDIM, 128, 16,  true ><<<NNODES / 8, 256, 0, stream>>>(x,  wr[0], wo[0], bs[0], offs, rev, hA);
    layer_kernel<128,  128, 128, true ><<<NNODES / 8, 256, 0, stream>>>(hA, wr[1], wo[1], bs[1], offs, rev, hB);
    layer_kernel<128,  128, 128, true ><<<NNODES / 8, 256, 0, stream>>>(hB, wr[2], wo[2], bs[2], offs, rev, hA);
    layer_kernel<128,  64,  128, false><<<NNODES / 8, 256, 0, stream>>>(hA, wr[3], wo[3], bs[3], offs, rev, hB);

    edge_kernel<<<dim3(16, 32, 16), 256, 0, stream>>>(hB, out);
}